// Round 11
// baseline (836.114 us; speedup 1.0000x reference)
//
#include <hip/hip_runtime.h>
#include <hip/hip_bf16.h>

// Problem constants
#define NB   64      // batch N
#define TT   12      // T
#define VV   256     // V (vertices)
#define CIN  64
#define COUT 64
#define VSQ  65536   // V*V
#define WT   16      // w-tile per fused block
#define VC   16      // v-chunk

typedef float f32x4 __attribute__((ext_vector_type(4)));
using s16x8 = __attribute__((ext_vector_type(8))) short;   // 8 bf16 (4 VGPRs)

__device__ __forceinline__ unsigned short f2bf(float f) {
    union { __hip_bfloat16 h; unsigned short u; } cv;
    cv.h = __float2bfloat16(f);          // RNE
    return cv.u;
}

// ---------------------------------------------------------------------------
// K1: y[n,o,t,v] = sum_c x[n,c,t,v] * conv_w[o,c] + conv_b[o]
// block = (n*T + t), 256 threads (thread = v). Proven ~20 us (BW floor).
// ---------------------------------------------------------------------------
__global__ __launch_bounds__(256) void k1_conv(
    const float* __restrict__ x, const float* __restrict__ w,
    const float* __restrict__ b, float* __restrict__ y)
{
    const int nt = blockIdx.x;
    const int n  = nt / TT;
    const int t  = nt % TT;
    const int v  = threadIdx.x;

    const float* xp = x + ((long)n * CIN * TT + t) * VV + v;
    float xv[CIN];
    #pragma unroll 8
    for (int c = 0; c < CIN; ++c)
        xv[c] = xp[(long)c * TT * VV];          // coalesced

    float* yp = y + ((long)n * COUT * TT + t) * VV + v;

    for (int o0 = 0; o0 < COUT; o0 += 16) {
        float acc[16];
        #pragma unroll
        for (int i = 0; i < 16; ++i) acc[i] = b[o0 + i];
        #pragma unroll 8
        for (int c = 0; c < CIN; ++c) {
            const float xc = xv[c];
            #pragma unroll
            for (int i = 0; i < 16; ++i)
                acc[i] += w[(o0 + i) * CIN + c] * xc;   // uniform -> s_load
        }
        #pragma unroll
        for (int i = 0; i < 16; ++i)
            yp[(long)(o0 + i) * TT * VV] = acc[i];
    }
}

// ---------------------------------------------------------------------------
// K23 fused v2 (MFMA layer-3, R10-proven fragment layouts).
// Block = (n, 16-w tile), n-major bid mapping (same-n blocks stride 64 apart
// -> same XCD under round-robin -> y L2 reuse). Per 16-v chunk:
//  Phase A (thread = (vj,wj)): h2[32] on VALU (624 FMA), bf16-pack into the
//    pre-swizzled afrag LDS tile (R10 layout), mask -> ms.
//  MFMA: wave handles M-tiles (=v) wave*4..+3, x 4 N-tiles (c): one
//    mfma_f32_16x16x32_bf16 each, C-init=b3, relu*mask, NORMAL f32x4 store
//    to Aw (required output; stays L2-resident).
//  Phase B (thread = (cb,wg)): re-read the chunk's Aw from L2 (post-barrier:
//    same CU, write-through L1 -> coherent) + y from global; accumulate
//    acc[t] (12 x f32x4). Kills the 1.07 GB Aw HBM re-read of the 3-kernel
//    structure. Epilogue: nontemporal out stores.
// ---------------------------------------------------------------------------
__global__ __launch_bounds__(256) void k23_fused(
    const float* __restrict__ A,
    const float* __restrict__ w1, const float* __restrict__ b1,
    const float* __restrict__ w2, const float* __restrict__ b2,
    const float* __restrict__ w3, const float* __restrict__ b3,
    const float* __restrict__ y,
    float* __restrict__ Aw, float* __restrict__ out)
{
    __shared__ unsigned int afrag[16 * 256];   // 16 KiB A-fragments
    __shared__ float ms[256];                  // mask per position

    const int n   = blockIdx.x & 63;           // n-major: same-n blocks -> same XCD
    const int w0  = (blockIdx.x >> 6) * WT;
    const int tid = threadIdx.x;

    const int vj   = tid >> 4;     // phase A: v within chunk
    const int wj   = tid & 15;     // phase A: w within tile
    const int lane = tid & 63;
    const int wave = tid >> 6;
    const int lc   = lane & 15;    // mfma: output-c lane
    const int lq   = lane >> 4;    // mfma: row quarter
    const int cb   = tid >> 2;     // phase B: c
    const int wg   = tid & 3;      // phase B: w-quad

    // B-fragments + biases, built once (R10-proven layout)
    s16x8 bfr[4];
    float bias[4];
    #pragma unroll
    for (int ntile = 0; ntile < 4; ++ntile) {
        const int c = ntile * 16 + lc;
        const float* wr = w3 + c * 32 + lq * 8;
        s16x8 bf;
        #pragma unroll
        for (int i = 0; i < 8; ++i) bf[i] = (short)f2bf(wr[i]);
        bfr[ntile]  = bf;
        bias[ntile] = b3[c];
    }

    f32x4 acc[TT];
    #pragma unroll
    for (int t = 0; t < TT; ++t) acc[t] = (f32x4)(0.f);

    const float* Abase = A + ((long)n * 8 << 16);
    float*       awn   = Aw + ((long)n * COUT << 16);
    const float* ybase = y + (long)(n * COUT + cb) * TT * VV;
    const float* awrd  = Aw + (((long)(n * COUT + cb)) << 16) + w0 + wg * 4;

    for (int v0 = 0; v0 < VV; v0 += VC) {
        // ---------------- phase A: h2 + pack ----------------
        {
            const int pos = (v0 + vj) * VV + (w0 + wj);
            const float* ap = Abase + pos;
            float f[7];
            #pragma unroll
            for (int c = 0; c < 7; ++c) f[c] = ap[(long)c << 16];
            ms[tid] = ap[(long)7 << 16];

            float h1[16];
            #pragma unroll
            for (int o = 0; o < 16; ++o) {
                float s = b1[o];
                #pragma unroll
                for (int k = 0; k < 7; ++k) s += w1[o * 7 + k] * f[k];   // uniform
                h1[o] = fmaxf(s, 0.f);
            }
            float h2[32];
            #pragma unroll
            for (int o = 0; o < 32; ++o) {
                float s = b2[o];
                #pragma unroll
                for (int k = 0; k < 16; ++k) s += w2[o * 16 + k] * h1[k]; // uniform
                h2[o] = fmaxf(s, 0.f);
            }
            #pragma unroll
            for (int kk = 0; kk < 16; ++kk) {
                const unsigned int pr = (unsigned int)f2bf(h2[2 * kk])
                                      | ((unsigned int)f2bf(h2[2 * kk + 1]) << 16);
                afrag[vj * 256 + (kk >> 2) * 64 + wj * 4 + (kk & 3)] = pr;
            }
        }
        __syncthreads();

        // ---------------- MFMA layer-3 + Aw store ----------------
        #pragma unroll
        for (int j = 0; j < 4; ++j) {
            const int mt = wave * 4 + j;                       // = v within chunk
            const s16x8 afr = *reinterpret_cast<const s16x8*>(&afrag[mt * 256 + lane * 4]);
            const int prow  = mt * 16 + lq * 4;                // position rows (w-major)
            const f32x4 mv  = *reinterpret_cast<const f32x4*>(&ms[prow]);
            const long  vrow = (long)(v0 + mt) * VV + w0 + lq * 4;
            #pragma unroll
            for (int ntile = 0; ntile < 4; ++ntile) {
                f32x4 a = (f32x4)(bias[ntile]);
                a = __builtin_amdgcn_mfma_f32_16x16x32_bf16(afr, bfr[ntile], a, 0, 0, 0);
                f32x4 r;
                #pragma unroll
                for (int u = 0; u < 4; ++u) r[u] = fmaxf(a[u], 0.f) * mv[u];
                *reinterpret_cast<f32x4*>(awn + ((long)(ntile * 16 + lc) << 16) + vrow) = r;
            }
        }
        __syncthreads();   // drain stores (L2-visible) + protect afrag/ms

        // ---------------- phase B: einsum partial ----------------
        f32x4 awv[VC];
        #pragma unroll
        for (int vv = 0; vv < VC; ++vv)
            awv[vv] = *reinterpret_cast<const f32x4*>(awrd + (long)(v0 + vv) * VV);  // L2 hit
        #pragma unroll
        for (int t = 0; t < TT; ++t) {
            #pragma unroll
            for (int q = 0; q < 4; ++q) {
                const f32x4 yv = *reinterpret_cast<const f32x4*>(ybase + t * VV + v0 + q * 4);
                acc[t] += yv.x * awv[q * 4 + 0] + yv.y * awv[q * 4 + 1]
                        + yv.z * awv[q * 4 + 2] + yv.w * awv[q * 4 + 3];
            }
        }
    }

    float* obase = out + (long)(n * COUT + cb) * TT * VV + w0 + wg * 4;
    #pragma unroll
    for (int t = 0; t < TT; ++t)
        __builtin_nontemporal_store(acc[t], reinterpret_cast<f32x4*>(obase + t * VV));
}

// ---------------------------------------------------------------------------
// Fallback path (ws too small): R10's proven K2 (MFMA) + K3.
// ---------------------------------------------------------------------------
__global__ __launch_bounds__(256) void k2_mlp(
    const float* __restrict__ A,
    const float* __restrict__ w1, const float* __restrict__ b1,
    const float* __restrict__ w2, const float* __restrict__ b2,
    const float* __restrict__ w3, const float* __restrict__ b3,
    float* __restrict__ Aw)
{
    __shared__ unsigned int afrag[16 * 256];
    __shared__ float ms[256];

    const int  tid  = threadIdx.x;
    const long gpos = (long)blockIdx.x * 256;
    const int  n    = (int)(gpos >> 16);
    const int  rem0 = (int)(gpos & (VSQ - 1));

    {
        const float* ap = A + ((long)n * 8 << 16) + rem0 + tid;
        float f[7];
        #pragma unroll
        for (int c = 0; c < 7; ++c) f[c] = ap[(long)c << 16];
        ms[tid] = ap[(long)7 << 16];

        float h1[16];
        #pragma unroll
        for (int o = 0; o < 16; ++o) {
            float s = b1[o];
            #pragma unroll
            for (int k = 0; k < 7; ++k) s += w1[o * 7 + k] * f[k];
            h1[o] = fmaxf(s, 0.f);
        }
        float h2[32];
        #pragma unroll
        for (int o = 0; o < 32; ++o) {
            float s = b2[o];
            #pragma unroll
            for (int k = 0; k < 16; ++k) s += w2[o * 16 + k] * h1[k];
            h2[o] = fmaxf(s, 0.f);
        }
        const int m = tid >> 4;
        const int r = tid & 15;
        #pragma unroll
        for (int kk = 0; kk < 16; ++kk) {
            const unsigned int pr = (unsigned int)f2bf(h2[2 * kk])
                                  | ((unsigned int)f2bf(h2[2 * kk + 1]) << 16);
            afrag[m * 256 + (kk >> 2) * 64 + r * 4 + (kk & 3)] = pr;
        }
    }
    __syncthreads();

    const int lane = tid & 63;
    const int wave = tid >> 6;
    const int lc   = lane & 15;
    const int lq   = lane >> 4;

    s16x8 bfr[4];
    float bias[4];
    #pragma unroll
    for (int ntile = 0; ntile < 4; ++ntile) {
        const int c = ntile * 16 + lc;
        const float* wr = w3 + c * 32 + lq * 8;
        s16x8 bf;
        #pragma unroll
        for (int i = 0; i < 8; ++i) bf[i] = (short)f2bf(wr[i]);
        bfr[ntile]  = bf;
        bias[ntile] = b3[c];
    }

    float* awbase = Aw + ((long)n * COUT << 16) + rem0;

    #pragma unroll
    for (int j = 0; j < 4; ++j) {
        const int mt = wave * 4 + j;
        const s16x8 afr = *reinterpret_cast<const s16x8*>(&afrag[mt * 256 + lane * 4]);
        const int pbase = mt * 16 + lq * 4;
        const f32x4 mv = *reinterpret_cast<const f32x4*>(&ms[pbase]);
        #pragma unroll
        for (int ntile = 0; ntile < 4; ++ntile) {
            f32x4 a = (f32x4)(bias[ntile]);
            a = __builtin_amdgcn_mfma_f32_16x16x32_bf16(afr, bfr[ntile], a, 0, 0, 0);
            f32x4 r;
            #pragma unroll
            for (int u = 0; u < 4; ++u) r[u] = fmaxf(a[u], 0.f) * mv[u];
            __builtin_nontemporal_store(r, reinterpret_cast<f32x4*>(
                awbase + ((long)(ntile * 16 + lc) << 16) + pbase));
        }
    }
}

__global__ __launch_bounds__(256) void k3_einsum(
    const float* __restrict__ Aw, const float* __restrict__ y,
    float* __restrict__ out)
{
    __shared__ float ys[4][TT][VV];

    const int n   = blockIdx.x >> 4;
    const int c0  = (blockIdx.x & 15) * 4;
    const int tid = threadIdx.x;
    const int cq  = tid >> 6;
    const int w4  = (tid & 63) * 4;

    {
        const float* src = y + ((long)(n * COUT + c0) * TT) * VV;
        float* dst = &ys[0][0][0];
        #pragma unroll
        for (int it = 0; it < 12; ++it) {
            const int idx = tid + it * 256;
            *reinterpret_cast<float4*>(dst + idx * 4) =
                *reinterpret_cast<const float4*>(src + idx * 4);
        }
    }
    __syncthreads();

    const float* awp = Aw + (((long)(n * COUT + c0 + cq)) << 16) + w4;
    float4 acc[TT];
    #pragma unroll
    for (int t = 0; t < TT; ++t) acc[t] = make_float4(0.f, 0.f, 0.f, 0.f);

    for (int v0 = 0; v0 < VV; v0 += 4) {
        float4 xs[TT];
        #pragma unroll
        for (int t = 0; t < TT; ++t)
            xs[t] = *reinterpret_cast<const float4*>(&ys[cq][t][v0]);

        const f32x4 aw0 = __builtin_nontemporal_load(
            reinterpret_cast<const f32x4*>(awp + (long)(v0 + 0) * VV));
        const f32x4 aw1 = __builtin_nontemporal_load(
            reinterpret_cast<const f32x4*>(awp + (long)(v0 + 1) * VV));
        const f32x4 aw2 = __builtin_nontemporal_load(
            reinterpret_cast<const f32x4*>(awp + (long)(v0 + 2) * VV));
        const f32x4 aw3 = __builtin_nontemporal_load(
            reinterpret_cast<const f32x4*>(awp + (long)(v0 + 3) * VV));

        #pragma unroll
        for (int t = 0; t < TT; ++t) {
            acc[t].x += xs[t].x * aw0.x + xs[t].y * aw1.x + xs[t].z * aw2.x + xs[t].w * aw3.x;
            acc[t].y += xs[t].x * aw0.y + xs[t].y * aw1.y + xs[t].z * aw2.y + xs[t].w * aw3.y;
            acc[t].z += xs[t].x * aw0.z + xs[t].y * aw1.z + xs[t].z * aw2.z + xs[t].w * aw3.z;
            acc[t].w += xs[t].x * aw0.w + xs[t].y * aw1.w + xs[t].z * aw2.w + xs[t].w * aw3.w;
        }
    }

    float* op = out + ((long)(n * COUT + c0 + cq) * TT) * VV + w4;
    #pragma unroll
    for (int t = 0; t < TT; ++t)
        *reinterpret_cast<float4*>(op + t * VV) = acc[t];
}

// ---------------------------------------------------------------------------
extern "C" void kernel_launch(void* const* d_in, const int* in_sizes, int n_in,
                              void* d_out, int out_size, void* d_ws, size_t ws_size,
                              hipStream_t stream)
{
    const float* x      = (const float*)d_in[0];
    const float* A      = (const float*)d_in[1];
    const float* conv_w = (const float*)d_in[2];
    const float* conv_b = (const float*)d_in[3];
    const float* w1     = (const float*)d_in[4];
    const float* b1     = (const float*)d_in[5];
    const float* w2     = (const float*)d_in[6];
    const float* b2     = (const float*)d_in[7];
    const float* w3     = (const float*)d_in[8];
    const float* b3     = (const float*)d_in[9];

    float* out = (float*)d_out;                                  // (64,64,12,256)
    float* Aw  = (float*)d_out + (long)NB * COUT * TT * VV;      // (64,64,256,256)
    const size_t y_bytes = (size_t)NB * COUT * TT * VV * sizeof(float);

    if (ws_size >= y_bytes) {
        float* y = (float*)d_ws;
        k1_conv<<<NB * TT, 256, 0, stream>>>(x, conv_w, conv_b, y);
        k23_fused<<<NB * (VV / WT), 256, 0, stream>>>(
            A, w1, b1, w2, b2, w3, b3, y, Aw, out);
    } else {
        k1_conv<<<NB * TT, 256, 0, stream>>>(x, conv_w, conv_b, out);
        k2_mlp<<<(NB * VSQ) / 256, 256, 0, stream>>>(A, w1, b1, w2, b2, w3, b3, Aw);
        k3_einsum<<<NB * (COUT / 4), 256, 0, stream>>>(Aw, out, out);
    }
}